// Round 1
// 1016.390 us; speedup vs baseline: 1.1363x; 1.1363x over previous
//
#include <hip/hip_runtime.h>
#include <hip/hip_bf16.h>

typedef unsigned short u16;
typedef unsigned int u32;

typedef __attribute__((ext_vector_type(8))) short bf16x8;
typedef __attribute__((ext_vector_type(4))) float f32x4;

__device__ __forceinline__ u16 f2bf(float f) {
    u32 u = __float_as_uint(f);
    u32 r = ((u >> 16) & 1u) + 0x7fffu;
    return (u16)((u + r) >> 16);
}
__device__ __forceinline__ float bf2f(u16 u) {
    return __uint_as_float(((u32)u) << 16);
}
// order-preserving float<->uint for atomicMax-based segment max
__device__ __forceinline__ u32 f2ord(float f) {
    u32 u = __float_as_uint(f);
    return (u & 0x80000000u) ? ~u : (u | 0x80000000u);
}
__device__ __forceinline__ float ord2f(u32 u) {
    return (u & 0x80000000u) ? __uint_as_float(u & 0x7fffffffu)
                             : __uint_as_float(~u);
}
__device__ __forceinline__ float leaky(float x) { return x >= 0.f ? x : 0.01f * x; }

// ---------------------------------------------------------------- prep:
// transpose W_edge[128,128] (f32) -> bf16 [n][k]   (W_msg stays f32, used in k_gru)
__global__ __launch_bounds__(256) void k_prep_transpose(
    const float* __restrict__ We, u16* __restrict__ WeT)
{
    int idx = blockIdx.x * 256 + threadIdx.x;   // grid=64 -> 0..16383
    int r = (idx >> 7) & 127;
    int c = idx & 127;
    WeT[c * 128 + r] = f2bf(We[r * 128 + c]);
}

// ---------------------------------------------------------------- CSR build
__global__ __launch_bounds__(256) void k_csr_count(
    const int* __restrict__ dst, u32* __restrict__ deg, int nE)
{
    long e = (long)blockIdx.x * 256 + threadIdx.x;
    if (e >= nE) return;
    atomicAdd(&deg[dst[e]], 1u);
}

// single block: exclusive scan of deg -> cur (scatter cursors)
__global__ __launch_bounds__(256) void k_csr_scan(
    const u32* __restrict__ deg, u32* __restrict__ cur, int nN)
{
    __shared__ u32 s[256];
    int t = threadIdx.x;
    int chunk = (nN + 255) / 256;
    int a = t * chunk;
    int b = a + chunk; if (b > nN) b = nN; if (a > nN) a = nN;
    u32 sum = 0;
    for (int i = a; i < b; i++) sum += deg[i];
    s[t] = sum;
    __syncthreads();
    for (int d = 1; d < 256; d <<= 1) {
        u32 v = (t >= d) ? s[t - d] : 0u;
        __syncthreads();
        s[t] += v;
        __syncthreads();
    }
    u32 base = (t == 0) ? 0u : s[t - 1];
    for (int i = a; i < b; i++) { cur[i] = base; base += deg[i]; }
}

__global__ __launch_bounds__(256) void k_csr_scatter(
    const int* __restrict__ src, const int* __restrict__ dst,
    u32* __restrict__ cur, int* __restrict__ sEidG,
    int* __restrict__ sSrcG, int* __restrict__ sDstG, int nE)
{
    long e = (long)blockIdx.x * 256 + threadIdx.x;
    if (e >= nE) return;
    int d = dst[e];
    u32 p = atomicAdd(&cur[d], 1u);
    sEidG[p] = (int)e;
    sSrcG[p] = src[e];
    sDstG[p] = d;
}

// ---------------------------------------------------------------- (1) node embed
// h_v = leaky(nf @ W_node + b_node)  [N,128] f32, 8 nodes/block, f32 VALU
__global__ __launch_bounds__(128) void k_node_embed(
    const float* __restrict__ nf, const float* __restrict__ Wn,
    const float* __restrict__ bn, float* __restrict__ h_v, int nN)
{
    __shared__ float sW[64][128];
    __shared__ float sF[8][64];
    int j = threadIdx.x;
    int n0 = blockIdx.x * 8;
    for (int i = 0; i < 64; i++) sW[i][j] = Wn[i * 128 + j];
    for (int t = j; t < 8 * 64; t += 128) {
        int n = t >> 6, k = t & 63;
        int nn = n0 + n; if (nn >= nN) nn = nN - 1;
        sF[n][k] = nf[(long)nn * 64 + k];
    }
    __syncthreads();
    float bj = bn[j];
    for (int n = 0; n < 8; n++) {
        if (n0 + n >= nN) break;
        float acc = bj;
        #pragma unroll 16
        for (int k = 0; k < 64; k++) acc += sF[n][k] * sW[k][j];
        h_v[(long)(n0 + n) * 128 + j] = leaky(acc);
    }
}

// stage e_in = [nf[src] | ef] (f32 -> bf16) into sIn[64][136]  (contiguous edges)
__device__ __forceinline__ void stage_ein(
    u16 (*sIn)[136], const float* nf, const float* ef,
    const int* sSrc, long e0, int nE, int tid)
{
    for (int c = tid; c < 64 * 32; c += 256) {   // 32 float4-chunks per edge
        int e = c >> 5, p = c & 31;
        long eg = e0 + e; if (eg >= nE) eg = nE - 1;
        float4 v;
        if (p < 16) v = *((const float4*)(nf + (long)sSrc[e] * 64 + p * 4));
        else        v = *((const float4*)(ef + eg * 64 + (p - 16) * 4));
        u32 lo = (u32)f2bf(v.x) | ((u32)f2bf(v.y) << 16);
        u32 hi = (u32)f2bf(v.z) | ((u32)f2bf(v.w) << 16);
        *((u32*)&sIn[e][p * 4])     = lo;
        *((u32*)&sIn[e][p * 4 + 2]) = hi;
    }
}

// ---------------------------------------------------------------- (2+3) fused
// edge embed (MFMA, LDS-only) + attention logit + segment max. 64 edges/block.
__global__ __launch_bounds__(256) void k_edge_logit(
    const float* __restrict__ nf, const float* __restrict__ ef,
    const int* __restrict__ src, const int* __restrict__ dst,
    const u16* __restrict__ WeT, const float* __restrict__ be,
    const float* __restrict__ WL, const float* __restrict__ bL,
    const float* __restrict__ h_v,
    float* __restrict__ logit, u32* __restrict__ lmax, int nE)
{
    __shared__ u16 sIn[64][136];
    __shared__ u16 sW[128][136];
    __shared__ u16 sHe[64][136];
    __shared__ float sWL[256];
    __shared__ int sSrc[64];
    int tid = threadIdx.x;
    long e0 = (long)blockIdx.x * 64;
    if (tid < 64) {
        long eg = e0 + tid; if (eg >= nE) eg = nE - 1;
        sSrc[tid] = src[eg];
    }
    sWL[tid] = WL[tid];
    __syncthreads();
    for (int c = tid; c < 2048; c += 256) {      // W_edge^T bf16, 16B chunks
        int r = c >> 4, p = c & 15;
        *((uint4*)&sW[r][p * 8]) = *((const uint4*)(WeT + r * 128 + p * 8));
    }
    stage_ein(sIn, nf, ef, sSrc, e0, nE, tid);
    __syncthreads();

    int lane = tid & 63, w = tid >> 6;
    int nl = lane & 15, q = lane >> 4;
    f32x4 acc[8];
    #pragma unroll
    for (int t = 0; t < 8; t++) acc[t] = (f32x4){0.f, 0.f, 0.f, 0.f};
    int eA = w * 16 + nl;                        // A row = lane&15
    #pragma unroll
    for (int s = 0; s < 4; s++) {
        int k0 = s * 32 + q * 8;                 // A/B k = quad*8 + j
        bf16x8 a = *((const bf16x8*)&sIn[eA][k0]);
        #pragma unroll
        for (int t = 0; t < 8; t++) {
            bf16x8 b = *((const bf16x8*)&sW[t * 16 + nl][k0]);
            acc[t] = __builtin_amdgcn_mfma_f32_16x16x32_bf16(a, b, acc[t], 0, 0, 0);
        }
    }
    // C/D: row = quad*4 + reg, col = lane&15
    #pragma unroll
    for (int t = 0; t < 8; t++) {
        int col = t * 16 + nl;
        float bias = be[col];
        #pragma unroll
        for (int r = 0; r < 4; r++) {
            int e = w * 16 + q * 4 + r;
            sHe[e][col] = f2bf(leaky(acc[t][r] + bias));
        }
    }
    __syncthreads();

    int e = tid >> 2;
    int sub = tid & 3;
    float sum = 0.f;
    if (sub < 2) {
        int s = sSrc[e];
        const float4* hv = (const float4*)(h_v + (long)s * 128 + sub * 64);
        #pragma unroll
        for (int i = 0; i < 16; i++) {
            float4 v = hv[i];
            int c = sub * 64 + i * 4;
            sum += v.x * sWL[c] + v.y * sWL[c + 1] + v.z * sWL[c + 2] + v.w * sWL[c + 3];
        }
    } else {
        #pragma unroll
        for (int i = 0; i < 16; i++) {
            int c0 = (sub - 2) * 64 + i * 4;
            sum += bf2f(sHe[e][c0])     * sWL[128 + c0]
                 + bf2f(sHe[e][c0 + 1]) * sWL[128 + c0 + 1]
                 + bf2f(sHe[e][c0 + 2]) * sWL[128 + c0 + 2]
                 + bf2f(sHe[e][c0 + 3]) * sWL[128 + c0 + 3];
        }
    }
    sum += __shfl_xor(sum, 1);
    sum += __shfl_xor(sum, 2);
    if (sub == 0 && e0 + e < nE) {
        float l = leaky(sum + bL[0]);
        logit[e0 + e] = l;
        atomicMax(&lmax[dst[e0 + e]], f2ord(l));
    }
}

// ---------------------------------------------------------------- (4) exp + denom
__global__ __launch_bounds__(256) void k_softmax_den(
    const int* __restrict__ dst, float* __restrict__ logit_ex,
    const u32* __restrict__ lmax, float* __restrict__ den, int nE)
{
    long e = (long)blockIdx.x * 256 + threadIdx.x;
    if (e >= nE) return;
    int d = dst[e];
    float ex = __expf(logit_ex[e] - ord2f(lmax[d]));
    logit_ex[e] = ex;
    atomicAdd(&den[d], ex);
}

// ---------------------------------------------------------------- (5) msg gather
// edges pre-sorted by dst. recompute h_e (MFMA), then A[v] += sum(alpha*h_e)
// with register-run segment reduction: atomics only at run boundaries.
// (W_msg matmul is hoisted to k_gru since sum(alpha)=1 per destination.)
__global__ __launch_bounds__(256) void k_msg_gather(
    const float* __restrict__ nf, const float* __restrict__ ef,
    const int* __restrict__ sEidG, const int* __restrict__ sSrcG,
    const int* __restrict__ sDstG,
    const u16* __restrict__ WeT, const float* __restrict__ be,
    const float* __restrict__ ex, const float* __restrict__ den,
    float* __restrict__ A, int nE)
{
    __shared__ u16 sIn[64][136];
    __shared__ u16 sW[128][136];
    __shared__ u16 sHe[64][136];
    __shared__ float sAlpha[64];
    __shared__ int sSrc[64];
    __shared__ int sEid[64];
    __shared__ int sDst[64];
    int tid = threadIdx.x;
    long p0 = (long)blockIdx.x * 64;
    if (tid < 64) {
        long p = p0 + tid;
        if (p < nE) {
            int eid = sEidG[p];
            int d = sDstG[p];
            sEid[tid] = eid;
            sSrc[tid] = sSrcG[p];
            sDst[tid] = d;
            sAlpha[tid] = ex[eid] / den[d];
        } else {
            sEid[tid] = sEidG[nE - 1];
            sSrc[tid] = sSrcG[nE - 1];
            sDst[tid] = sDstG[nE - 1];
            sAlpha[tid] = 0.f;           // contributes nothing
        }
    }
    __syncthreads();
    for (int c = tid; c < 2048; c += 256) {      // W_edge^T bf16
        int r = c >> 4, p = c & 15;
        *((uint4*)&sW[r][p * 8]) = *((const uint4*)(WeT + r * 128 + p * 8));
    }
    // stage e_in gathered via sorted eid/src
    for (int c = tid; c < 64 * 32; c += 256) {
        int e = c >> 5, p = c & 31;
        float4 v;
        if (p < 16) v = *((const float4*)(nf + (long)sSrc[e] * 64 + p * 4));
        else        v = *((const float4*)(ef + (long)sEid[e] * 64 + (p - 16) * 4));
        u32 lo = (u32)f2bf(v.x) | ((u32)f2bf(v.y) << 16);
        u32 hi = (u32)f2bf(v.z) | ((u32)f2bf(v.w) << 16);
        *((u32*)&sIn[e][p * 4])     = lo;
        *((u32*)&sIn[e][p * 4 + 2]) = hi;
    }
    __syncthreads();

    int lane = tid & 63, w = tid >> 6;
    int nl = lane & 15, q = lane >> 4;
    f32x4 acc[8];
    #pragma unroll
    for (int t = 0; t < 8; t++) acc[t] = (f32x4){0.f, 0.f, 0.f, 0.f};
    int eA = w * 16 + nl;
    #pragma unroll
    for (int s = 0; s < 4; s++) {
        int k0 = s * 32 + q * 8;
        bf16x8 a = *((const bf16x8*)&sIn[eA][k0]);
        #pragma unroll
        for (int t = 0; t < 8; t++) {
            bf16x8 b = *((const bf16x8*)&sW[t * 16 + nl][k0]);
            acc[t] = __builtin_amdgcn_mfma_f32_16x16x32_bf16(a, b, acc[t], 0, 0, 0);
        }
    }
    #pragma unroll
    for (int t = 0; t < 8; t++) {
        int col = t * 16 + nl;
        float bias = be[col];
        #pragma unroll
        for (int r = 0; r < 4; r++) {
            int e = w * 16 + q * 4 + r;
            sHe[e][col] = f2bf(leaky(acc[t][r] + bias));
        }
    }
    __syncthreads();

    // weighted segment-sum: wave w owns edges [w*16, w*16+16), lane covers
    // cols (lane, lane+64). dst runs are wave-uniform -> coalesced flushes.
    int eb = w * 16;
    float sx = 0.f, sy = 0.f;
    int curd = sDst[eb];
    for (int i = 0; i < 16; i++) {
        int e = eb + i;
        float a = sAlpha[e];
        sx += a * bf2f(sHe[e][lane]);
        sy += a * bf2f(sHe[e][lane + 64]);
        int nxt = (i == 15) ? -1 : sDst[e + 1];
        if (nxt != curd) {
            atomicAdd(&A[(long)curd * 128 + lane], sx);
            atomicAdd(&A[(long)curd * 128 + lane + 64], sy);
            sx = 0.f; sy = 0.f;
            curd = nxt;
        }
    }
}

// ---------------------------------------------------------------- (6) ctx + GRU
// C_v = elu(A_v @ W_msg + b_msg) for deg>0 (den>0), else 0; then GRUCell.
__global__ __launch_bounds__(128) void k_gru(
    const float* __restrict__ h_v, const float* __restrict__ A,
    const float* __restrict__ Wm, const float* __restrict__ bm,
    const float* __restrict__ den,
    const float* __restrict__ Wih, const float* __restrict__ Whh,
    const float* __restrict__ bih, const float* __restrict__ bhh,
    float* __restrict__ out, int nN)
{
    __shared__ float sA[8][128];
    __shared__ float sC[8][128];
    __shared__ float sH[8][128];
    int j = threadIdx.x;
    int n0 = blockIdx.x * 8;
    for (int n = 0; n < 8; n++) {
        int nn = n0 + n; if (nn >= nN) nn = nN - 1;
        sA[n][j] = A[(long)nn * 128 + j];
        sH[n][j] = h_v[(long)nn * 128 + j];
    }
    __syncthreads();
    // C = elu(A @ Wm + bm)   (Wm[k][j] f32, coalesced over j, L2-resident)
    float cc[8];
    {
        float bmj = bm[j];
        #pragma unroll
        for (int n = 0; n < 8; n++) cc[n] = bmj;
        for (int k = 0; k < 128; k++) {
            float wk = Wm[(long)k * 128 + j];
            #pragma unroll
            for (int n = 0; n < 8; n++) cc[n] += sA[n][k] * wk;
        }
    }
    for (int n = 0; n < 8; n++) {
        int nn = n0 + n; if (nn >= nN) nn = nN - 1;
        float c = cc[n];
        sC[n][j] = (den[nn] > 0.f) ? (c > 0.f ? c : __expf(c) - 1.f) : 0.f;
    }
    __syncthreads();
    float gi[3][8], gh[3][8];
    #pragma unroll
    for (int g = 0; g < 3; g++) {
        float bi = bih[g * 128 + j];
        float bh = bhh[g * 128 + j];
        #pragma unroll
        for (int n = 0; n < 8; n++) { gi[g][n] = bi; gh[g][n] = bh; }
    }
    for (int k = 0; k < 128; k += 4) {
        float4 cv[8], hv[8];
        #pragma unroll
        for (int n = 0; n < 8; n++) {
            cv[n] = *(const float4*)&sC[n][k];
            hv[n] = *(const float4*)&sH[n][k];
        }
        #pragma unroll
        for (int g = 0; g < 3; g++) {
            float4 wi = *((const float4*)(Wih + (long)(g * 128 + j) * 128 + k));
            float4 wh = *((const float4*)(Whh + (long)(g * 128 + j) * 128 + k));
            #pragma unroll
            for (int n = 0; n < 8; n++) {
                gi[g][n] += wi.x * cv[n].x + wi.y * cv[n].y + wi.z * cv[n].z + wi.w * cv[n].w;
                gh[g][n] += wh.x * hv[n].x + wh.y * hv[n].y + wh.z * hv[n].z + wh.w * hv[n].w;
            }
        }
    }
    #pragma unroll
    for (int n = 0; n < 8; n++) {
        if (n0 + n >= nN) break;
        float r = 1.f / (1.f + __expf(-(gi[0][n] + gh[0][n])));
        float z = 1.f / (1.f + __expf(-(gi[1][n] + gh[1][n])));
        float nn = tanhf(gi[2][n] + r * gh[2][n]);
        float h = (1.f - z) * nn + z * sH[n][j];
        out[(long)(n0 + n) * 128 + j] = (h > 0.f ? h : 0.f);
    }
}

extern "C" void kernel_launch(void* const* d_in, const int* in_sizes, int n_in,
                              void* d_out, int out_size, void* d_ws, size_t ws_size,
                              hipStream_t stream) {
    // All float tensors are FLOAT32 per the reference (jnp.float32).
    const float* nf  = (const float*)d_in[0];
    const float* ef  = (const float*)d_in[1];
    const float* Wn  = (const float*)d_in[2];
    const float* bn  = (const float*)d_in[3];
    const float* We  = (const float*)d_in[4];
    const float* be  = (const float*)d_in[5];
    const float* WL  = (const float*)d_in[6];
    const float* bL  = (const float*)d_in[7];
    const float* Wm  = (const float*)d_in[8];
    const float* bm  = (const float*)d_in[9];
    const float* Wih = (const float*)d_in[10];
    const float* Whh = (const float*)d_in[11];
    const float* bih = (const float*)d_in[12];
    const float* bhh = (const float*)d_in[13];
    const int* src = (const int*)d_in[14];
    const int* dst = (const int*)d_in[15];
    float* out = (float*)d_out;

    int nN = in_sizes[0] / 64;        // node count (NF=64)
    int nE = in_sizes[1] / 64;        // edge count (EF=64)

    char* w = (char*)d_ws;
    float* h_v   = (float*)w;  w += (size_t)nN * 128 * 4;
    float* logit = (float*)w;  w += (size_t)nE * 4;
    // ---- zeroed region start ----
    u32*   lmax  = (u32*)w;    w += ((size_t)nN + 256) * 4;
    float* den   = (float*)w;  w += ((size_t)nN + 256) * 4;
    float* Cacc  = (float*)w;  w += (size_t)nN * 128 * 4;
    u32*   deg   = (u32*)w;    w += (size_t)nN * 4;
    // ---- zeroed region end ----
    u32*   cur   = (u32*)w;    w += (size_t)nN * 4;
    int*   sEid  = (int*)w;    w += (size_t)nE * 4;
    int*   sSrc  = (int*)w;    w += (size_t)nE * 4;
    int*   sDst  = (int*)w;    w += (size_t)nE * 4;
    u16*   WeT   = (u16*)w;    w += 128 * 128 * 2;

    size_t zbytes = ((size_t)nN + 256) * 4 * 2 + (size_t)nN * 128 * 4
                  + (size_t)nN * 4;
    hipMemsetAsync(lmax, 0, zbytes, stream);

    int gN8   = (nN + 7) / 8;
    int gE64  = (nE + 63) / 64;
    int gE256 = (nE + 255) / 256;

    k_prep_transpose<<<64, 256, 0, stream>>>(We, WeT);
    k_csr_count<<<gE256, 256, 0, stream>>>(dst, deg, nE);
    k_csr_scan<<<1, 256, 0, stream>>>(deg, cur, nN);
    k_csr_scatter<<<gE256, 256, 0, stream>>>(src, dst, cur, sEid, sSrc, sDst, nE);
    k_node_embed<<<gN8, 128, 0, stream>>>(nf, Wn, bn, h_v, nN);
    k_edge_logit<<<gE64, 256, 0, stream>>>(nf, ef, src, dst, WeT, be,
                                           WL, bL, h_v, logit, lmax, nE);
    k_softmax_den<<<gE256, 256, 0, stream>>>(dst, logit, lmax, den, nE);
    k_msg_gather<<<gE64, 256, 0, stream>>>(nf, ef, sEid, sSrc, sDst, WeT, be,
                                           logit, den, Cacc, nE);
    k_gru<<<gN8, 128, 0, stream>>>(h_v, Cacc, Wm, bm, den,
                                   Wih, Whh, bih, bhh, out, nN);

    // passthrough edge_feats (f32) -> second output
    hipMemcpyAsync(out + (size_t)nN * 128, ef, (size_t)nE * 64 * 4,
                   hipMemcpyDeviceToDevice, stream);
}

// Round 2
// 829.446 us; speedup vs baseline: 1.3924x; 1.2254x over previous
//
#include <hip/hip_runtime.h>
#include <hip/hip_bf16.h>

typedef unsigned short u16;
typedef unsigned int u32;

typedef __attribute__((ext_vector_type(8))) short bf16x8;
typedef __attribute__((ext_vector_type(4))) float f32x4;

__device__ __forceinline__ u16 f2bf(float f) {
    u32 u = __float_as_uint(f);
    u32 r = ((u >> 16) & 1u) + 0x7fffu;
    return (u16)((u + r) >> 16);
}
__device__ __forceinline__ float bf2f(u16 u) {
    return __uint_as_float(((u32)u) << 16);
}
__device__ __forceinline__ float leaky(float x) { return x >= 0.f ? x : 0.01f * x; }

// ---------------------------------------------------------------- prep:
// transpose W_edge[128,128] (f32) -> bf16 [n][k]
__global__ __launch_bounds__(256) void k_prep_transpose(
    const float* __restrict__ We, u16* __restrict__ WeT)
{
    int idx = blockIdx.x * 256 + threadIdx.x;   // grid=64 -> 0..16383
    int r = (idx >> 7) & 127;
    int c = idx & 127;
    WeT[c * 128 + r] = f2bf(We[r * 128 + c]);
}

// ---------------------------------------------------------------- CSR build
__global__ __launch_bounds__(256) void k_csr_count(
    const int* __restrict__ dst, u32* __restrict__ deg, int nE)
{
    long e = (long)blockIdx.x * 256 + threadIdx.x;
    if (e >= nE) return;
    atomicAdd(&deg[dst[e]], 1u);
}

// single block: exclusive scan of deg -> start (row offsets) + cur (cursors)
__global__ __launch_bounds__(256) void k_csr_scan(
    const u32* __restrict__ deg, u32* __restrict__ start,
    u32* __restrict__ cur, int nN)
{
    __shared__ u32 s[256];
    int t = threadIdx.x;
    int chunk = (nN + 255) / 256;
    int a = t * chunk;
    int b = a + chunk; if (b > nN) b = nN; if (a > nN) a = nN;
    u32 sum = 0;
    for (int i = a; i < b; i++) sum += deg[i];
    s[t] = sum;
    __syncthreads();
    for (int d = 1; d < 256; d <<= 1) {
        u32 v = (t >= d) ? s[t - d] : 0u;
        __syncthreads();
        s[t] += v;
        __syncthreads();
    }
    u32 base = (t == 0) ? 0u : s[t - 1];
    for (int i = a; i < b; i++) { start[i] = base; cur[i] = base; base += deg[i]; }
}

__global__ __launch_bounds__(256) void k_csr_scatter(
    const int* __restrict__ src, const int* __restrict__ dst,
    u32* __restrict__ cur, int* __restrict__ sEidG,
    int* __restrict__ sSrcG, int* __restrict__ sDstG,
    int* __restrict__ rank, int nE)
{
    long e = (long)blockIdx.x * 256 + threadIdx.x;
    if (e >= nE) return;
    int d = dst[e];
    u32 p = atomicAdd(&cur[d], 1u);
    sEidG[p] = (int)e;
    sSrcG[p] = src[e];
    sDstG[p] = d;
    rank[e] = (int)p;
}

// ---------------------------------------------------------------- (1) node embed
// h_v = leaky(nf @ W_node + b_node); also g_v = h_v . WL[0:128] (logit hoist)
__global__ __launch_bounds__(128) void k_node_embed(
    const float* __restrict__ nf, const float* __restrict__ Wn,
    const float* __restrict__ bn, const float* __restrict__ WL,
    float* __restrict__ h_v, float* __restrict__ g, int nN)
{
    __shared__ float sW[64][128];
    __shared__ float sF[8][64];
    __shared__ float sRed[2][8];
    int j = threadIdx.x;
    int n0 = blockIdx.x * 8;
    for (int i = 0; i < 64; i++) sW[i][j] = Wn[i * 128 + j];
    for (int t = j; t < 8 * 64; t += 128) {
        int n = t >> 6, k = t & 63;
        int nn = n0 + n; if (nn >= nN) nn = nN - 1;
        sF[n][k] = nf[(long)nn * 64 + k];
    }
    __syncthreads();
    float bj = bn[j];
    float wl = WL[j];
    int wv = j >> 6, ln = j & 63;
    float hval[8];
    for (int n = 0; n < 8; n++) {
        float acc = bj;
        #pragma unroll 16
        for (int k = 0; k < 64; k++) acc += sF[n][k] * sW[k][j];
        float h = leaky(acc);
        hval[n] = h;
        if (n0 + n < nN) h_v[(long)(n0 + n) * 128 + j] = h;
    }
    #pragma unroll
    for (int n = 0; n < 8; n++) {
        float part = hval[n] * wl;
        #pragma unroll
        for (int o = 1; o < 64; o <<= 1) part += __shfl_xor(part, o);
        if (ln == 0) sRed[wv][n] = part;
    }
    __syncthreads();
    if (j < 8 && n0 + j < nN) g[n0 + j] = sRed[0][j] + sRed[1][j];
}

// stage e_in = [nf[src] | ef] (f32 -> bf16) into sIn[64][136]  (contiguous edges)
__device__ __forceinline__ void stage_ein(
    u16 (*sIn)[136], const float* nf, const float* ef,
    const int* sSrc, long e0, int nE, int tid)
{
    for (int c = tid; c < 64 * 32; c += 256) {   // 32 float4-chunks per edge
        int e = c >> 5, p = c & 31;
        long eg = e0 + e; if (eg >= nE) eg = nE - 1;
        float4 v;
        if (p < 16) v = *((const float4*)(nf + (long)sSrc[e] * 64 + p * 4));
        else        v = *((const float4*)(ef + eg * 64 + (p - 16) * 4));
        u32 lo = (u32)f2bf(v.x) | ((u32)f2bf(v.y) << 16);
        u32 hi = (u32)f2bf(v.z) | ((u32)f2bf(v.w) << 16);
        *((u32*)&sIn[e][p * 4])     = lo;
        *((u32*)&sIn[e][p * 4 + 2]) = hi;
    }
}

// ---------------------------------------------------------------- (2+3) fused
// edge embed (MFMA) + logit (g[src] + h_e.WL2) -> logitS[rank]; optional he store.
// sHe aliases sIn (all post-MFMA access is wave-local rows [16w,16w+16)).
template<bool WRITE_HE>
__global__ __launch_bounds__(256) void k_edge_logit(
    const float* __restrict__ nf, const float* __restrict__ ef,
    const int* __restrict__ src, const int* __restrict__ rank,
    const u16* __restrict__ WeT, const float* __restrict__ be,
    const float* __restrict__ WL, const float* __restrict__ bL,
    const float* __restrict__ g,
    float* __restrict__ logitS, u16* __restrict__ heG, int nE)
{
    __shared__ u16 sW[128][136];
    __shared__ u16 sIn[64][136];          // input tile, then h_e tile (aliased)
    __shared__ float sWL2[128];
    __shared__ int sSrc[64];
    __shared__ int sRank[64];
    int tid = threadIdx.x;
    long e0 = (long)blockIdx.x * 64;
    if (tid < 64) {
        long eg = e0 + tid; if (eg >= nE) eg = nE - 1;
        sSrc[tid] = src[eg];
        sRank[tid] = rank[eg];
    } else if (tid < 192) {
        sWL2[tid - 64] = WL[tid + 64];    // WL[128 + (tid-64)]
    }
    __syncthreads();
    for (int c = tid; c < 2048; c += 256) {      // W_edge^T bf16, 16B chunks
        int r = c >> 4, p = c & 15;
        *((uint4*)&sW[r][p * 8]) = *((const uint4*)(WeT + r * 128 + p * 8));
    }
    stage_ein(sIn, nf, ef, sSrc, e0, nE, tid);
    __syncthreads();

    int lane = tid & 63, w = tid >> 6;
    int nl = lane & 15, q = lane >> 4;
    f32x4 acc[8];
    #pragma unroll
    for (int t = 0; t < 8; t++) acc[t] = (f32x4){0.f, 0.f, 0.f, 0.f};
    int eA = w * 16 + nl;                        // A row = lane&15 (wave-local rows)
    #pragma unroll
    for (int s = 0; s < 4; s++) {
        int k0 = s * 32 + q * 8;                 // A/B k = quad*8 + j
        bf16x8 a = *((const bf16x8*)&sIn[eA][k0]);
        #pragma unroll
        for (int t = 0; t < 8; t++) {
            bf16x8 b = *((const bf16x8*)&sW[t * 16 + nl][k0]);
            acc[t] = __builtin_amdgcn_mfma_f32_16x16x32_bf16(a, b, acc[t], 0, 0, 0);
        }
    }
    // C/D: row = quad*4 + reg, col = lane&15 ; overwrite own sIn rows with h_e
    #pragma unroll
    for (int t = 0; t < 8; t++) {
        int col = t * 16 + nl;
        float bias = be[col];
        #pragma unroll
        for (int r = 0; r < 4; r++) {
            int e = w * 16 + q * 4 + r;
            sIn[e][col] = f2bf(leaky(acc[t][r] + bias));
        }
    }
    // wave-local copy of own h_e rows to global (coalesced 1KB per instr)
    if (WRITE_HE) {
        #pragma unroll
        for (int i = 0; i < 4; i++) {
            int row = w * 16 + i * 4 + (lane >> 4);
            int ch = lane & 15;
            long eg = e0 + row;
            uint4 v4 = *((const uint4*)&sIn[row][ch * 8]);
            if (eg < nE) *((uint4*)(heG + eg * 128 + ch * 8)) = v4;
        }
    }
    // logit phase, wave-local: 4 lanes per edge, 32 cols each
    int ew = lane >> 2, sub = lane & 3;
    int e = w * 16 + ew;
    float sum = 0.f;
    #pragma unroll
    for (int i = 0; i < 4; i++) {
        bf16x8 hv = *((const bf16x8*)&sIn[e][sub * 32 + i * 8]);
        #pragma unroll
        for (int jj = 0; jj < 8; jj++)
            sum += bf2f((u16)hv[jj]) * sWL2[sub * 32 + i * 8 + jj];
    }
    sum += __shfl_xor(sum, 1);
    sum += __shfl_xor(sum, 2);
    if (sub == 0 && e0 + e < nE) {
        float l = leaky(sum + g[sSrc[e]] + bL[0]);
        logitS[sRank[e]] = l;
    }
}

// ---------------------------------------------------------------- (4) per-node softmax
// logitS rows are contiguous per destination (CSR). in-place logit -> alpha.
__global__ __launch_bounds__(256) void k_softmax_node(
    const u32* __restrict__ start, const u32* __restrict__ deg,
    float* __restrict__ logitS, int nN)
{
    int v = blockIdx.x * 4 + (threadIdx.x >> 6);
    int lane = threadIdx.x & 63;
    if (v >= nN) return;
    u32 d = deg[v];
    if (d == 0) return;
    u32 s0 = start[v];
    float mx = -3.402823e38f;
    for (u32 i = lane; i < d; i += 64) mx = fmaxf(mx, logitS[s0 + i]);
    #pragma unroll
    for (int o = 1; o < 64; o <<= 1) mx = fmaxf(mx, __shfl_xor(mx, o));
    float sum = 0.f;
    for (u32 i = lane; i < d; i += 64) {
        float e = __expf(logitS[s0 + i] - mx);
        logitS[s0 + i] = e;
        sum += e;
    }
    #pragma unroll
    for (int o = 1; o < 64; o <<= 1) sum += __shfl_xor(sum, o);
    float inv = 1.f / sum;
    for (u32 i = lane; i < d; i += 64) logitS[s0 + i] *= inv;
}

// ---------------------------------------------------------------- (5a) msg lite:
// stream stored h_e (bf16) in sorted order; register run segment-sum -> A.
__global__ __launch_bounds__(256) void k_msg_lite(
    const u16* __restrict__ heG, const float* __restrict__ alphaS,
    const int* __restrict__ sEidG, const int* __restrict__ sDstG,
    float* __restrict__ A, int nE)
{
    __shared__ float sAl[256];
    __shared__ int sEid[256];
    __shared__ int sDst[256];
    int tid = threadIdx.x;
    long p0 = (long)blockIdx.x * 256;
    long p = p0 + tid;
    if (p < nE) {
        sAl[tid] = alphaS[p];
        sEid[tid] = sEidG[p];
        sDst[tid] = sDstG[p];
    } else {
        sAl[tid] = 0.f;
        sEid[tid] = sEidG[nE - 1];
        sDst[tid] = sDstG[nE - 1];
    }
    __syncthreads();
    int lane = tid & 63, w = tid >> 6;
    int i0 = w * 64;
    float sx = 0.f, sy = 0.f;
    int curd = sDst[i0];
    #pragma unroll 4
    for (int i = 0; i < 64; i++) {
        int idx = i0 + i;
        float a = sAl[idx];
        const u16* row = heG + (long)sEid[idx] * 128;
        sx += a * bf2f(row[lane]);
        sy += a * bf2f(row[lane + 64]);
        int nxt = (i == 63) ? -1 : sDst[idx + 1];
        if (nxt != curd) {
            atomicAdd(&A[(long)curd * 128 + lane], sx);
            atomicAdd(&A[(long)curd * 128 + lane + 64], sy);
            sx = 0.f; sy = 0.f;
            curd = nxt;
        }
    }
}

// ---------------------------------------------------------------- (5b) msg heavy:
// fallback when ws too small for he: recompute h_e via MFMA (sHe aliases sIn).
__global__ __launch_bounds__(256) void k_msg_heavy(
    const float* __restrict__ nf, const float* __restrict__ ef,
    const int* __restrict__ sEidG, const int* __restrict__ sSrcG,
    const int* __restrict__ sDstG,
    const u16* __restrict__ WeT, const float* __restrict__ be,
    const float* __restrict__ alphaS,
    float* __restrict__ A, int nE)
{
    __shared__ u16 sW[128][136];
    __shared__ u16 sIn[64][136];
    __shared__ float sAlpha[64];
    __shared__ int sSrc[64];
    __shared__ int sEid[64];
    __shared__ int sDst[64];
    int tid = threadIdx.x;
    long p0 = (long)blockIdx.x * 64;
    if (tid < 64) {
        long p = p0 + tid;
        if (p < nE) {
            sEid[tid] = sEidG[p];
            sSrc[tid] = sSrcG[p];
            sDst[tid] = sDstG[p];
            sAlpha[tid] = alphaS[p];
        } else {
            sEid[tid] = sEidG[nE - 1];
            sSrc[tid] = sSrcG[nE - 1];
            sDst[tid] = sDstG[nE - 1];
            sAlpha[tid] = 0.f;
        }
    }
    __syncthreads();
    for (int c = tid; c < 2048; c += 256) {
        int r = c >> 4, pp = c & 15;
        *((uint4*)&sW[r][pp * 8]) = *((const uint4*)(WeT + r * 128 + pp * 8));
    }
    for (int c = tid; c < 64 * 32; c += 256) {
        int e = c >> 5, pp = c & 31;
        float4 v;
        if (pp < 16) v = *((const float4*)(nf + (long)sSrc[e] * 64 + pp * 4));
        else         v = *((const float4*)(ef + (long)sEid[e] * 64 + (pp - 16) * 4));
        u32 lo = (u32)f2bf(v.x) | ((u32)f2bf(v.y) << 16);
        u32 hi = (u32)f2bf(v.z) | ((u32)f2bf(v.w) << 16);
        *((u32*)&sIn[e][pp * 4])     = lo;
        *((u32*)&sIn[e][pp * 4 + 2]) = hi;
    }
    __syncthreads();

    int lane = tid & 63, w = tid >> 6;
    int nl = lane & 15, q = lane >> 4;
    f32x4 acc[8];
    #pragma unroll
    for (int t = 0; t < 8; t++) acc[t] = (f32x4){0.f, 0.f, 0.f, 0.f};
    int eA = w * 16 + nl;
    #pragma unroll
    for (int s = 0; s < 4; s++) {
        int k0 = s * 32 + q * 8;
        bf16x8 a = *((const bf16x8*)&sIn[eA][k0]);
        #pragma unroll
        for (int t = 0; t < 8; t++) {
            bf16x8 b = *((const bf16x8*)&sW[t * 16 + nl][k0]);
            acc[t] = __builtin_amdgcn_mfma_f32_16x16x32_bf16(a, b, acc[t], 0, 0, 0);
        }
    }
    #pragma unroll
    for (int t = 0; t < 8; t++) {
        int col = t * 16 + nl;
        float bias = be[col];
        #pragma unroll
        for (int r = 0; r < 4; r++) {
            int e = w * 16 + q * 4 + r;
            sIn[e][col] = f2bf(leaky(acc[t][r] + bias));
        }
    }
    // wave-local segment sum over own 16 rows
    int eb = w * 16;
    float sx = 0.f, sy = 0.f;
    int curd = sDst[eb];
    for (int i = 0; i < 16; i++) {
        int e = eb + i;
        float a = sAlpha[e];
        sx += a * bf2f(sIn[e][lane]);
        sy += a * bf2f(sIn[e][lane + 64]);
        int nxt = (i == 15) ? -1 : sDst[e + 1];
        if (nxt != curd) {
            atomicAdd(&A[(long)curd * 128 + lane], sx);
            atomicAdd(&A[(long)curd * 128 + lane + 64], sy);
            sx = 0.f; sy = 0.f;
            curd = nxt;
        }
    }
}

// ---------------------------------------------------------------- (6) ctx + GRU
__global__ __launch_bounds__(128) void k_gru(
    const float* __restrict__ h_v, const float* __restrict__ A,
    const float* __restrict__ Wm, const float* __restrict__ bm,
    const u32* __restrict__ deg,
    const float* __restrict__ Wih, const float* __restrict__ Whh,
    const float* __restrict__ bih, const float* __restrict__ bhh,
    float* __restrict__ out, int nN)
{
    __shared__ float sA[8][128];
    __shared__ float sC[8][128];
    __shared__ float sH[8][128];
    int j = threadIdx.x;
    int n0 = blockIdx.x * 8;
    for (int n = 0; n < 8; n++) {
        int nn = n0 + n; if (nn >= nN) nn = nN - 1;
        sA[n][j] = A[(long)nn * 128 + j];
        sH[n][j] = h_v[(long)nn * 128 + j];
    }
    __syncthreads();
    float cc[8];
    {
        float bmj = bm[j];
        #pragma unroll
        for (int n = 0; n < 8; n++) cc[n] = bmj;
        for (int k = 0; k < 128; k++) {
            float wk = Wm[(long)k * 128 + j];
            #pragma unroll
            for (int n = 0; n < 8; n++) cc[n] += sA[n][k] * wk;
        }
    }
    for (int n = 0; n < 8; n++) {
        int nn = n0 + n; if (nn >= nN) nn = nN - 1;
        float c = cc[n];
        sC[n][j] = (deg[nn] > 0u) ? (c > 0.f ? c : __expf(c) - 1.f) : 0.f;
    }
    __syncthreads();
    float gi[3][8], gh[3][8];
    #pragma unroll
    for (int g = 0; g < 3; g++) {
        float bi = bih[g * 128 + j];
        float bh = bhh[g * 128 + j];
        #pragma unroll
        for (int n = 0; n < 8; n++) { gi[g][n] = bi; gh[g][n] = bh; }
    }
    for (int k = 0; k < 128; k += 4) {
        float4 cv[8], hv[8];
        #pragma unroll
        for (int n = 0; n < 8; n++) {
            cv[n] = *(const float4*)&sC[n][k];
            hv[n] = *(const float4*)&sH[n][k];
        }
        #pragma unroll
        for (int g = 0; g < 3; g++) {
            float4 wi = *((const float4*)(Wih + (long)(g * 128 + j) * 128 + k));
            float4 wh = *((const float4*)(Whh + (long)(g * 128 + j) * 128 + k));
            #pragma unroll
            for (int n = 0; n < 8; n++) {
                gi[g][n] += wi.x * cv[n].x + wi.y * cv[n].y + wi.z * cv[n].z + wi.w * cv[n].w;
                gh[g][n] += wh.x * hv[n].x + wh.y * hv[n].y + wh.z * hv[n].z + wh.w * hv[n].w;
            }
        }
    }
    #pragma unroll
    for (int n = 0; n < 8; n++) {
        if (n0 + n >= nN) break;
        float r = 1.f / (1.f + __expf(-(gi[0][n] + gh[0][n])));
        float z = 1.f / (1.f + __expf(-(gi[1][n] + gh[1][n])));
        float nn = tanhf(gi[2][n] + r * gh[2][n]);
        float h = (1.f - z) * nn + z * sH[n][j];
        out[(long)(n0 + n) * 128 + j] = (h > 0.f ? h : 0.f);
    }
}

extern "C" void kernel_launch(void* const* d_in, const int* in_sizes, int n_in,
                              void* d_out, int out_size, void* d_ws, size_t ws_size,
                              hipStream_t stream) {
    const float* nf  = (const float*)d_in[0];
    const float* ef  = (const float*)d_in[1];
    const float* Wn  = (const float*)d_in[2];
    const float* bn  = (const float*)d_in[3];
    const float* We  = (const float*)d_in[4];
    const float* be  = (const float*)d_in[5];
    const float* WL  = (const float*)d_in[6];
    const float* bL  = (const float*)d_in[7];
    const float* Wm  = (const float*)d_in[8];
    const float* bm  = (const float*)d_in[9];
    const float* Wih = (const float*)d_in[10];
    const float* Whh = (const float*)d_in[11];
    const float* bih = (const float*)d_in[12];
    const float* bhh = (const float*)d_in[13];
    const int* src = (const int*)d_in[14];
    const int* dst = (const int*)d_in[15];
    float* out = (float*)d_out;

    int nN = in_sizes[0] / 64;        // node count (NF=64)
    int nE = in_sizes[1] / 64;        // edge count (EF=64)

    size_t o = 0;
    auto nxt = [&](size_t b) { size_t p = o; o += (b + 255) & ~(size_t)255; return p; };
    size_t o_hv    = nxt((size_t)nN * 128 * 4);
    size_t o_g     = nxt((size_t)nN * 4);
    size_t o_logit = nxt((size_t)nE * 4);
    size_t o_A     = nxt((size_t)nN * 128 * 4);   // zeroed
    size_t o_deg   = nxt((size_t)nN * 4);         // zeroed
    size_t o_start = nxt((size_t)nN * 4);
    size_t o_cur   = nxt((size_t)nN * 4);
    size_t o_eid   = nxt((size_t)nE * 4);
    size_t o_srcS  = nxt((size_t)nE * 4);
    size_t o_dstS  = nxt((size_t)nE * 4);
    size_t o_rank  = nxt((size_t)nE * 4);
    size_t o_WeT   = nxt((size_t)128 * 128 * 2);
    size_t o_he    = nxt((size_t)nE * 128 * 2);   // optional (lite path)
    bool lite = (o <= ws_size);

    char* w = (char*)d_ws;
    float* h_v    = (float*)(w + o_hv);
    float* g      = (float*)(w + o_g);
    float* logitS = (float*)(w + o_logit);
    float* A      = (float*)(w + o_A);
    u32*   deg    = (u32*)(w + o_deg);
    u32*   start  = (u32*)(w + o_start);
    u32*   cur    = (u32*)(w + o_cur);
    int*   sEid   = (int*)(w + o_eid);
    int*   sSrcS  = (int*)(w + o_srcS);
    int*   sDstS  = (int*)(w + o_dstS);
    int*   rank   = (int*)(w + o_rank);
    u16*   WeT    = (u16*)(w + o_WeT);
    u16*   heG    = (u16*)(w + o_he);

    // zero A + deg (contiguous incl. pad)
    hipMemsetAsync(A, 0, o_start - o_A, stream);

    int gN8   = (nN + 7) / 8;
    int gN4   = (nN + 3) / 4;
    int gE64  = (nE + 63) / 64;
    int gE256 = (nE + 255) / 256;

    k_prep_transpose<<<64, 256, 0, stream>>>(We, WeT);
    k_csr_count<<<gE256, 256, 0, stream>>>(dst, deg, nE);
    k_csr_scan<<<1, 256, 0, stream>>>(deg, start, cur, nN);
    k_csr_scatter<<<gE256, 256, 0, stream>>>(src, dst, cur, sEid, sSrcS, sDstS, rank, nE);
    k_node_embed<<<gN8, 128, 0, stream>>>(nf, Wn, bn, WL, h_v, g, nN);
    if (lite) {
        k_edge_logit<true><<<gE64, 256, 0, stream>>>(
            nf, ef, src, rank, WeT, be, WL, bL, g, logitS, heG, nE);
    } else {
        k_edge_logit<false><<<gE64, 256, 0, stream>>>(
            nf, ef, src, rank, WeT, be, WL, bL, g, logitS, heG, nE);
    }
    k_softmax_node<<<gN4, 256, 0, stream>>>(start, deg, logitS, nN);
    if (lite) {
        k_msg_lite<<<gE256, 256, 0, stream>>>(heG, logitS, sEid, sDstS, A, nE);
    } else {
        k_msg_heavy<<<gE64, 256, 0, stream>>>(nf, ef, sEid, sSrcS, sDstS,
                                              WeT, be, logitS, A, nE);
    }
    k_gru<<<gN8, 128, 0, stream>>>(h_v, A, Wm, bm, deg,
                                   Wih, Whh, bih, bhh, out, nN);

    // passthrough edge_feats (f32) -> second output
    hipMemcpyAsync(out + (size_t)nN * 128, ef, (size_t)nE * 64 * 4,
                   hipMemcpyDeviceToDevice, stream);
}

// Round 3
// 746.807 us; speedup vs baseline: 1.5465x; 1.1107x over previous
//
#include <hip/hip_runtime.h>
#include <hip/hip_bf16.h>

typedef unsigned short u16;
typedef unsigned int u32;

typedef __attribute__((ext_vector_type(8))) short bf16x8;
typedef __attribute__((ext_vector_type(4))) float f32x4;

__device__ __forceinline__ u16 f2bf(float f) {
    u32 u = __float_as_uint(f);
    u32 r = ((u >> 16) & 1u) + 0x7fffu;
    return (u16)((u + r) >> 16);
}
__device__ __forceinline__ float bf2f(u16 u) {
    return __uint_as_float(((u32)u) << 16);
}
__device__ __forceinline__ float leaky(float x) { return x >= 0.f ? x : 0.01f * x; }

// ---------------------------------------------------------------- prep:
// transpose W_edge[128,128] (f32) -> bf16 [n][k]
__global__ __launch_bounds__(256) void k_prep_transpose(
    const float* __restrict__ We, u16* __restrict__ WeT)
{
    int idx = blockIdx.x * 256 + threadIdx.x;   // grid=64 -> 0..16383
    int r = (idx >> 7) & 127;
    int c = idx & 127;
    WeT[c * 128 + r] = f2bf(We[r * 128 + c]);
}

// ---------------------------------------------------------------- CSR build
__global__ __launch_bounds__(256) void k_csr_count(
    const int* __restrict__ dst, u32* __restrict__ deg, int nE)
{
    long e = (long)blockIdx.x * 256 + threadIdx.x;
    if (e >= nE) return;
    atomicAdd(&deg[dst[e]], 1u);
}

// single block: exclusive scan of deg -> start (row offsets) + cur (cursors)
__global__ __launch_bounds__(256) void k_csr_scan(
    const u32* __restrict__ deg, u32* __restrict__ start,
    u32* __restrict__ cur, int nN)
{
    __shared__ u32 s[256];
    int t = threadIdx.x;
    int chunk = (nN + 255) / 256;
    int a = t * chunk;
    int b = a + chunk; if (b > nN) b = nN; if (a > nN) a = nN;
    u32 sum = 0;
    for (int i = a; i < b; i++) sum += deg[i];
    s[t] = sum;
    __syncthreads();
    for (int d = 1; d < 256; d <<= 1) {
        u32 v = (t >= d) ? s[t - d] : 0u;
        __syncthreads();
        s[t] += v;
        __syncthreads();
    }
    u32 base = (t == 0) ? 0u : s[t - 1];
    for (int i = a; i < b; i++) { start[i] = base; cur[i] = base; base += deg[i]; }
}

__global__ __launch_bounds__(256) void k_csr_scatter(
    const int* __restrict__ src, const int* __restrict__ dst,
    u32* __restrict__ cur, int* __restrict__ sEidG,
    int* __restrict__ sSrcG, int* __restrict__ sDstG, int nE)
{
    long e = (long)blockIdx.x * 256 + threadIdx.x;
    if (e >= nE) return;
    int d = dst[e];
    u32 p = atomicAdd(&cur[d], 1u);
    sEidG[p] = (int)e;
    sSrcG[p] = src[e];
    sDstG[p] = d;
}

// ---------------------------------------------------------------- (1) node embed
// h_v = leaky(nf @ W_node + b_node); also g_v = h_v . WL[0:128] (logit hoist)
__global__ __launch_bounds__(128) void k_node_embed(
    const float* __restrict__ nf, const float* __restrict__ Wn,
    const float* __restrict__ bn, const float* __restrict__ WL,
    float* __restrict__ h_v, float* __restrict__ g, int nN)
{
    __shared__ float sW[64][128];
    __shared__ float sF[8][64];
    __shared__ float sRed[2][8];
    int j = threadIdx.x;
    int n0 = blockIdx.x * 8;
    for (int i = 0; i < 64; i++) sW[i][j] = Wn[i * 128 + j];
    for (int t = j; t < 8 * 64; t += 128) {
        int n = t >> 6, k = t & 63;
        int nn = n0 + n; if (nn >= nN) nn = nN - 1;
        sF[n][k] = nf[(long)nn * 64 + k];
    }
    __syncthreads();
    float bj = bn[j];
    float wl = WL[j];
    int wv = j >> 6, ln = j & 63;
    float hval[8];
    for (int n = 0; n < 8; n++) {
        float acc = bj;
        #pragma unroll 16
        for (int k = 0; k < 64; k++) acc += sF[n][k] * sW[k][j];
        float h = leaky(acc);
        hval[n] = h;
        if (n0 + n < nN) h_v[(long)(n0 + n) * 128 + j] = h;
    }
    #pragma unroll
    for (int n = 0; n < 8; n++) {
        float part = hval[n] * wl;
        #pragma unroll
        for (int o = 1; o < 64; o <<= 1) part += __shfl_xor(part, o);
        if (ln == 0) sRed[wv][n] = part;
    }
    __syncthreads();
    if (j < 8 && n0 + j < nN) g[n0 + j] = sRed[0][j] + sRed[1][j];
}

// ---------------------------------------------------------------- (2+3) fused
// Processes edges in dst-sorted (CSR) order: block owns sorted positions
// [p0,p0+64). Gathers nf[src]/ef[eid]; MFMA edge embed with W split in two
// 64-row passes (LDS 36KB -> 4 blocks/CU); writes he[p] + logitS[p]
// contiguous; also streams the ef passthrough (replaces the D2D memcpy).
template<bool WRITE_HE>
__global__ __launch_bounds__(256, 4) void k_edge_logit(
    const float* __restrict__ nf, const float* __restrict__ ef,
    const int* __restrict__ sEidG, const int* __restrict__ sSrcG,
    const u16* __restrict__ WeT, const float* __restrict__ be,
    const float* __restrict__ WL, const float* __restrict__ bL,
    const float* __restrict__ g,
    float* __restrict__ logitS, u16* __restrict__ heG,
    float* __restrict__ efOut, int nE)
{
    __shared__ u16 sW[64][136];           // half of W_edge^T at a time
    __shared__ u16 sIn[64][136];          // input tile, then h_e tile (aliased)
    __shared__ float sWL2[128];
    __shared__ float sG[64];
    __shared__ int sSrc[64];
    __shared__ int sEid[64];
    int tid = threadIdx.x;
    long p0 = (long)blockIdx.x * 64;
    if (tid < 64) {
        long p = p0 + tid; if (p >= nE) p = nE - 1;
        int eid = sEidG[p];
        int s = sSrcG[p];
        sEid[tid] = eid;
        sSrc[tid] = s;
        sG[tid] = g[s];
    } else if (tid < 192) {
        sWL2[tid - 64] = WL[64 + tid];    // WL[128 + (tid-64)]
    }
    __syncthreads();
    // stage W pass-1 rows [0,64) + input tile; fold in ef passthrough store
    for (int c = tid; c < 1024; c += 256) {
        int r = c >> 4, p = c & 15;
        *((uint4*)&sW[r][p * 8]) = *((const uint4*)(WeT + r * 128 + p * 8));
    }
    for (int c = tid; c < 2048; c += 256) {
        int e = c >> 5, p = c & 31;
        float4 v;
        if (p < 16) {
            v = *((const float4*)(nf + (long)sSrc[e] * 64 + p * 4));
        } else {
            v = *((const float4*)(ef + (long)sEid[e] * 64 + (p - 16) * 4));
            if (p0 + e < nE)
                *((float4*)(efOut + (long)sEid[e] * 64 + (p - 16) * 4)) = v;
        }
        u32 lo = (u32)f2bf(v.x) | ((u32)f2bf(v.y) << 16);
        u32 hi = (u32)f2bf(v.z) | ((u32)f2bf(v.w) << 16);
        *((u32*)&sIn[e][p * 4])     = lo;
        *((u32*)&sIn[e][p * 4 + 2]) = hi;
    }
    __syncthreads();

    int lane = tid & 63, w = tid >> 6;
    int nl = lane & 15, q = lane >> 4;
    int eA = w * 16 + nl;                 // A row (wave-local rows)
    bf16x8 afr[4];
    #pragma unroll
    for (int s = 0; s < 4; s++)
        afr[s] = *((const bf16x8*)&sIn[eA][s * 32 + q * 8]);
    f32x4 acc[8];
    #pragma unroll
    for (int t = 0; t < 8; t++) acc[t] = (f32x4){0.f, 0.f, 0.f, 0.f};
    // pass 1: output cols [0,64)
    #pragma unroll
    for (int s = 0; s < 4; s++) {
        int k0 = s * 32 + q * 8;
        #pragma unroll
        for (int t = 0; t < 4; t++) {
            bf16x8 b = *((const bf16x8*)&sW[t * 16 + nl][k0]);
            acc[t] = __builtin_amdgcn_mfma_f32_16x16x32_bf16(afr[s], b, acc[t], 0, 0, 0);
        }
    }
    __syncthreads();                      // all waves done with W pass-1
    for (int c = tid; c < 1024; c += 256) {
        int r = c >> 4, p = c & 15;
        *((uint4*)&sW[r][p * 8]) = *((const uint4*)(WeT + (64 + r) * 128 + p * 8));
    }
    __syncthreads();
    // pass 2: output cols [64,128)
    #pragma unroll
    for (int s = 0; s < 4; s++) {
        int k0 = s * 32 + q * 8;
        #pragma unroll
        for (int t = 0; t < 4; t++) {
            bf16x8 b = *((const bf16x8*)&sW[t * 16 + nl][k0]);
            acc[4 + t] = __builtin_amdgcn_mfma_f32_16x16x32_bf16(afr[s], b, acc[4 + t], 0, 0, 0);
        }
    }
    // epilogue: h_e -> own sIn rows (wave-local, no barrier needed)
    #pragma unroll
    for (int t = 0; t < 8; t++) {
        int col = t * 16 + nl;
        float bias = be[col];
        #pragma unroll
        for (int r = 0; r < 4; r++) {
            int e = w * 16 + q * 4 + r;
            sIn[e][col] = f2bf(leaky(acc[t][r] + bias));
        }
    }
    // contiguous he store (sorted order)
    if (WRITE_HE) {
        #pragma unroll
        for (int i = 0; i < 4; i++) {
            int row = w * 16 + i * 4 + (lane >> 4);
            int ch = lane & 15;
            long pg = p0 + row;
            uint4 v4 = *((const uint4*)&sIn[row][ch * 8]);
            if (pg < nE) *((uint4*)(heG + pg * 128 + ch * 8)) = v4;
        }
    }
    // logit phase, wave-local: 4 lanes per edge, 32 cols each
    int ew = lane >> 2, sub = lane & 3;
    int e = w * 16 + ew;
    float sum = 0.f;
    #pragma unroll
    for (int i = 0; i < 4; i++) {
        bf16x8 hv = *((const bf16x8*)&sIn[e][sub * 32 + i * 8]);
        #pragma unroll
        for (int jj = 0; jj < 8; jj++)
            sum += bf2f((u16)hv[jj]) * sWL2[sub * 32 + i * 8 + jj];
    }
    sum += __shfl_xor(sum, 1);
    sum += __shfl_xor(sum, 2);
    if (sub == 0 && p0 + e < nE) {
        float l = leaky(sum + sG[e] + bL[0]);
        logitS[p0 + e] = l;
    }
}

// ---------------------------------------------------------------- (4+5) fused
// wave per node: softmax over contiguous logitS run + weighted stream-sum of
// contiguous heG rows -> A[v]. No atomics, no zero-init.
__global__ __launch_bounds__(256) void k_softmax_msg(
    const u32* __restrict__ start, const u32* __restrict__ deg,
    const u16* __restrict__ heG, float* __restrict__ logitS,
    float* __restrict__ A, int nN)
{
    __shared__ float sAl[4][1024];
    int wv = threadIdx.x >> 6, lane = threadIdx.x & 63;
    int v = blockIdx.x * 4 + wv;
    if (v >= nN) return;
    long base = (long)v * 128;
    u32 d = deg[v];
    if (d == 0) {
        A[base + lane] = 0.f;
        A[base + lane + 64] = 0.f;
        return;
    }
    u32 s0 = start[v];
    float mx = -3.402823e38f;
    for (u32 i = lane; i < d; i += 64) mx = fmaxf(mx, logitS[s0 + i]);
    #pragma unroll
    for (int o = 1; o < 64; o <<= 1) mx = fmaxf(mx, __shfl_xor(mx, o));
    float sum = 0.f;
    for (u32 i = lane; i < d; i += 64) {
        float e_ = __expf(logitS[s0 + i] - mx);
        sum += e_;
        if (i < 1024) sAl[wv][i] = e_;
        else logitS[s0 + i] = e_;      // rare overflow spill
    }
    #pragma unroll
    for (int o = 1; o < 64; o <<= 1) sum += __shfl_xor(sum, o);
    float inv = 1.f / sum;
    // weighted sum of he rows; lane covers cols (2*lane, 2*lane+1)
    float ax = 0.f, ay = 0.f;
    #pragma unroll 4
    for (u32 i = 0; i < d; i++) {
        float al = (i < 1024) ? sAl[wv][i] : logitS[s0 + i];
        u32 rw = *((const u32*)(heG + ((long)(s0 + i)) * 128 + lane * 2));
        ax += al * bf2f((u16)(rw & 0xffffu));
        ay += al * bf2f((u16)(rw >> 16));
    }
    A[base + lane * 2]     = ax * inv;
    A[base + lane * 2 + 1] = ay * inv;
}

// ---------------------------------------------------------------- (4b) fallback softmax
__global__ __launch_bounds__(256) void k_softmax_node(
    const u32* __restrict__ start, const u32* __restrict__ deg,
    float* __restrict__ logitS, int nN)
{
    int v = blockIdx.x * 4 + (threadIdx.x >> 6);
    int lane = threadIdx.x & 63;
    if (v >= nN) return;
    u32 d = deg[v];
    if (d == 0) return;
    u32 s0 = start[v];
    float mx = -3.402823e38f;
    for (u32 i = lane; i < d; i += 64) mx = fmaxf(mx, logitS[s0 + i]);
    #pragma unroll
    for (int o = 1; o < 64; o <<= 1) mx = fmaxf(mx, __shfl_xor(mx, o));
    float sum = 0.f;
    for (u32 i = lane; i < d; i += 64) {
        float e = __expf(logitS[s0 + i] - mx);
        logitS[s0 + i] = e;
        sum += e;
    }
    #pragma unroll
    for (int o = 1; o < 64; o <<= 1) sum += __shfl_xor(sum, o);
    float inv = 1.f / sum;
    for (u32 i = lane; i < d; i += 64) logitS[s0 + i] *= inv;
}

// ---------------------------------------------------------------- (5b) fallback msg:
// recompute h_e via MFMA (sorted inputs), run-sum with boundary atomics.
__global__ __launch_bounds__(256) void k_msg_heavy(
    const float* __restrict__ nf, const float* __restrict__ ef,
    const int* __restrict__ sEidG, const int* __restrict__ sSrcG,
    const int* __restrict__ sDstG,
    const u16* __restrict__ WeT, const float* __restrict__ be,
    const float* __restrict__ alphaS,
    float* __restrict__ A, int nE)
{
    __shared__ u16 sW[128][136];
    __shared__ u16 sIn[64][136];
    __shared__ float sAlpha[64];
    __shared__ int sSrc[64];
    __shared__ int sEid[64];
    __shared__ int sDst[64];
    int tid = threadIdx.x;
    long p0 = (long)blockIdx.x * 64;
    if (tid < 64) {
        long p = p0 + tid;
        if (p < nE) {
            sEid[tid] = sEidG[p];
            sSrc[tid] = sSrcG[p];
            sDst[tid] = sDstG[p];
            sAlpha[tid] = alphaS[p];
        } else {
            sEid[tid] = sEidG[nE - 1];
            sSrc[tid] = sSrcG[nE - 1];
            sDst[tid] = sDstG[nE - 1];
            sAlpha[tid] = 0.f;
        }
    }
    __syncthreads();
    for (int c = tid; c < 2048; c += 256) {
        int r = c >> 4, pp = c & 15;
        *((uint4*)&sW[r][pp * 8]) = *((const uint4*)(WeT + r * 128 + pp * 8));
    }
    for (int c = tid; c < 64 * 32; c += 256) {
        int e = c >> 5, pp = c & 31;
        float4 v;
        if (pp < 16) v = *((const float4*)(nf + (long)sSrc[e] * 64 + pp * 4));
        else         v = *((const float4*)(ef + (long)sEid[e] * 64 + (pp - 16) * 4));
        u32 lo = (u32)f2bf(v.x) | ((u32)f2bf(v.y) << 16);
        u32 hi = (u32)f2bf(v.z) | ((u32)f2bf(v.w) << 16);
        *((u32*)&sIn[e][pp * 4])     = lo;
        *((u32*)&sIn[e][pp * 4 + 2]) = hi;
    }
    __syncthreads();

    int lane = tid & 63, w = tid >> 6;
    int nl = lane & 15, q = lane >> 4;
    f32x4 acc[8];
    #pragma unroll
    for (int t = 0; t < 8; t++) acc[t] = (f32x4){0.f, 0.f, 0.f, 0.f};
    int eA = w * 16 + nl;
    #pragma unroll
    for (int s = 0; s < 4; s++) {
        int k0 = s * 32 + q * 8;
        bf16x8 a = *((const bf16x8*)&sIn[eA][k0]);
        #pragma unroll
        for (int t = 0; t < 8; t++) {
            bf16x8 b = *((const bf16x8*)&sW[t * 16 + nl][k0]);
            acc[t] = __builtin_amdgcn_mfma_f32_16x16x32_bf16(a, b, acc[t], 0, 0, 0);
        }
    }
    #pragma unroll
    for (int t = 0; t < 8; t++) {
        int col = t * 16 + nl;
        float bias = be[col];
        #pragma unroll
        for (int r = 0; r < 4; r++) {
            int e = w * 16 + q * 4 + r;
            sIn[e][col] = f2bf(leaky(acc[t][r] + bias));
        }
    }
    int eb = w * 16;
    float sx = 0.f, sy = 0.f;
    int curd = sDst[eb];
    for (int i = 0; i < 16; i++) {
        int e = eb + i;
        float a = sAlpha[e];
        sx += a * bf2f(sIn[e][lane]);
        sy += a * bf2f(sIn[e][lane + 64]);
        int nxt = (i == 15) ? -1 : sDst[e + 1];
        if (nxt != curd) {
            atomicAdd(&A[(long)curd * 128 + lane], sx);
            atomicAdd(&A[(long)curd * 128 + lane + 64], sy);
            sx = 0.f; sy = 0.f;
            curd = nxt;
        }
    }
}

// ---------------------------------------------------------------- (6) ctx + GRU
__global__ __launch_bounds__(128) void k_gru(
    const float* __restrict__ h_v, const float* __restrict__ A,
    const float* __restrict__ Wm, const float* __restrict__ bm,
    const u32* __restrict__ deg,
    const float* __restrict__ Wih, const float* __restrict__ Whh,
    const float* __restrict__ bih, const float* __restrict__ bhh,
    float* __restrict__ out, int nN)
{
    __shared__ float sA[8][128];
    __shared__ float sC[8][128];
    __shared__ float sH[8][128];
    int j = threadIdx.x;
    int n0 = blockIdx.x * 8;
    for (int n = 0; n < 8; n++) {
        int nn = n0 + n; if (nn >= nN) nn = nN - 1;
        sA[n][j] = A[(long)nn * 128 + j];
        sH[n][j] = h_v[(long)nn * 128 + j];
    }
    __syncthreads();
    float cc[8];
    {
        float bmj = bm[j];
        #pragma unroll
        for (int n = 0; n < 8; n++) cc[n] = bmj;
        for (int k = 0; k < 128; k++) {
            float wk = Wm[(long)k * 128 + j];
            #pragma unroll
            for (int n = 0; n < 8; n++) cc[n] += sA[n][k] * wk;
        }
    }
    for (int n = 0; n < 8; n++) {
        int nn = n0 + n; if (nn >= nN) nn = nN - 1;
        float c = cc[n];
        sC[n][j] = (deg[nn] > 0u) ? (c > 0.f ? c : __expf(c) - 1.f) : 0.f;
    }
    __syncthreads();
    float gi[3][8], gh[3][8];
    #pragma unroll
    for (int g = 0; g < 3; g++) {
        float bi = bih[g * 128 + j];
        float bh = bhh[g * 128 + j];
        #pragma unroll
        for (int n = 0; n < 8; n++) { gi[g][n] = bi; gh[g][n] = bh; }
    }
    for (int k = 0; k < 128; k += 4) {
        float4 cv[8], hv[8];
        #pragma unroll
        for (int n = 0; n < 8; n++) {
            cv[n] = *(const float4*)&sC[n][k];
            hv[n] = *(const float4*)&sH[n][k];
        }
        #pragma unroll
        for (int g = 0; g < 3; g++) {
            float4 wi = *((const float4*)(Wih + (long)(g * 128 + j) * 128 + k));
            float4 wh = *((const float4*)(Whh + (long)(g * 128 + j) * 128 + k));
            #pragma unroll
            for (int n = 0; n < 8; n++) {
                gi[g][n] += wi.x * cv[n].x + wi.y * cv[n].y + wi.z * cv[n].z + wi.w * cv[n].w;
                gh[g][n] += wh.x * hv[n].x + wh.y * hv[n].y + wh.z * hv[n].z + wh.w * hv[n].w;
            }
        }
    }
    #pragma unroll
    for (int n = 0; n < 8; n++) {
        if (n0 + n >= nN) break;
        float r = 1.f / (1.f + __expf(-(gi[0][n] + gh[0][n])));
        float z = 1.f / (1.f + __expf(-(gi[1][n] + gh[1][n])));
        float nn = tanhf(gi[2][n] + r * gh[2][n]);
        float h = (1.f - z) * nn + z * sH[n][j];
        out[(long)(n0 + n) * 128 + j] = (h > 0.f ? h : 0.f);
    }
}

extern "C" void kernel_launch(void* const* d_in, const int* in_sizes, int n_in,
                              void* d_out, int out_size, void* d_ws, size_t ws_size,
                              hipStream_t stream) {
    const float* nf  = (const float*)d_in[0];
    const float* ef  = (const float*)d_in[1];
    const float* Wn  = (const float*)d_in[2];
    const float* bn  = (const float*)d_in[3];
    const float* We  = (const float*)d_in[4];
    const float* be  = (const float*)d_in[5];
    const float* WL  = (const float*)d_in[6];
    const float* bL  = (const float*)d_in[7];
    const float* Wm  = (const float*)d_in[8];
    const float* bm  = (const float*)d_in[9];
    const float* Wih = (const float*)d_in[10];
    const float* Whh = (const float*)d_in[11];
    const float* bih = (const float*)d_in[12];
    const float* bhh = (const float*)d_in[13];
    const int* src = (const int*)d_in[14];
    const int* dst = (const int*)d_in[15];
    float* out = (float*)d_out;

    int nN = in_sizes[0] / 64;        // node count (NF=64)
    int nE = in_sizes[1] / 64;        // edge count (EF=64)

    size_t o = 0;
    auto nxt = [&](size_t b) { size_t p = o; o += (b + 255) & ~(size_t)255; return p; };
    size_t o_hv    = nxt((size_t)nN * 128 * 4);
    size_t o_g     = nxt((size_t)nN * 4);
    size_t o_logit = nxt((size_t)nE * 4);
    size_t o_A     = nxt((size_t)nN * 128 * 4);   // zeroed only in fallback
    size_t o_deg   = nxt((size_t)nN * 4);         // zeroed
    size_t o_start = nxt((size_t)nN * 4);
    size_t o_cur   = nxt((size_t)nN * 4);
    size_t o_eid   = nxt((size_t)nE * 4);
    size_t o_srcS  = nxt((size_t)nE * 4);
    size_t o_dstS  = nxt((size_t)nE * 4);
    size_t o_WeT   = nxt((size_t)128 * 128 * 2);
    size_t o_he    = nxt((size_t)nE * 128 * 2);   // lite path only
    bool lite = (o <= ws_size);

    char* w = (char*)d_ws;
    float* h_v    = (float*)(w + o_hv);
    float* g      = (float*)(w + o_g);
    float* logitS = (float*)(w + o_logit);
    float* A      = (float*)(w + o_A);
    u32*   deg    = (u32*)(w + o_deg);
    u32*   start  = (u32*)(w + o_start);
    u32*   cur    = (u32*)(w + o_cur);
    int*   sEid   = (int*)(w + o_eid);
    int*   sSrcS  = (int*)(w + o_srcS);
    int*   sDstS  = (int*)(w + o_dstS);
    u16*   WeT    = (u16*)(w + o_WeT);
    u16*   heG    = (u16*)(w + o_he);
    float* efOut  = out + (size_t)nN * 128;       // second output (passthrough)

    if (lite) {
        hipMemsetAsync(deg, 0, (size_t)nN * 4, stream);
    } else {
        // fallback uses atomics into A -> zero A + deg (contiguous)
        hipMemsetAsync(A, 0, o_start - o_A, stream);
    }

    int gN8   = (nN + 7) / 8;
    int gN4   = (nN + 3) / 4;
    int gE64  = (nE + 63) / 64;
    int gE256 = (nE + 255) / 256;

    k_prep_transpose<<<64, 256, 0, stream>>>(We, WeT);
    k_csr_count<<<gE256, 256, 0, stream>>>(dst, deg, nE);
    k_csr_scan<<<1, 256, 0, stream>>>(deg, start, cur, nN);
    k_csr_scatter<<<gE256, 256, 0, stream>>>(src, dst, cur, sEid, sSrcS, sDstS, nE);
    k_node_embed<<<gN8, 128, 0, stream>>>(nf, Wn, bn, WL, h_v, g, nN);
    if (lite) {
        k_edge_logit<true><<<gE64, 256, 0, stream>>>(
            nf, ef, sEid, sSrcS, WeT, be, WL, bL, g, logitS, heG, efOut, nE);
        k_softmax_msg<<<gN4, 256, 0, stream>>>(start, deg, heG, logitS, A, nN);
    } else {
        k_edge_logit<false><<<gE64, 256, 0, stream>>>(
            nf, ef, sEid, sSrcS, WeT, be, WL, bL, g, logitS, heG, efOut, nE);
        k_softmax_node<<<gN4, 256, 0, stream>>>(start, deg, logitS, nN);
        k_msg_heavy<<<gE64, 256, 0, stream>>>(nf, ef, sEid, sSrcS, sDstS,
                                              WeT, be, logitS, A, nE);
    }
    k_gru<<<gN8, 128, 0, stream>>>(h_v, A, Wm, bm, deg,
                                   Wih, Whh, bih, bhh, out, nN);
}